// Round 12
// baseline (241.823 us; speedup 1.0000x reference)
//
#include <hip/hip_runtime.h>
#include <math.h>

#define NPTS 4096
#define EPSV 1e-5f

// ---------------------------------------------------------------------------
// K0: pack q = (x, y, z, -|q|^2) per batch point from the flat-view columns
// P_n = (buf[n], buf[4096+n], buf[8192+n]). One-time, coalesced.
// ---------------------------------------------------------------------------
__global__ __launch_bounds__(256) void k_pack(const float* __restrict__ x,
                                              float4* __restrict__ qpack) {
  const int i = blockIdx.x * 256 + threadIdx.x;  // 0..32767
  const int b = i >> 12, m = i & 4095;
  const float* xb = x + b * 12288;
  float a0 = xb[m], a1 = xb[NPTS + m], a2 = xb[2 * NPTS + m];
  float w = -fmaf(a2, a2, fmaf(a1, a1, a0 * a0));
  qpack[i] = make_float4(a0, a1, a2, w);
}

// ---------------------------------------------------------------------------
// K1: stage-1 KNN via the SCALAR pipe (R12).
// R3-R11 invariant: every variant streamed q per-pair through a shared per-CU
// pipe (LDS broadcast ~12cyc/b128 => ~41us floor, or L2 vector loads when the
// allocator rematerialized) -- the VALU was never the bottleneck. Fix: q is
// WAVE-UNIFORM here (lane owns p, wave iterates q), so q arrives via
// s_load_dwordx4 on the scalar/SMEM path; the hot loop has zero LDS and zero
// vector-memory traffic. Chunk id forced wave-uniform via readfirstlane.
// key(q) = 2p.q - |q|^2 (per-p shift dropped; order-preserving; identical fma
// chain everywhere). Per q-iter: ~5 VALU covers 64 pairs. Per-lane top-3 with
// strict > (ascending scan = lax.top_k stable order); 4 scanners x 1024-chunk
// per p, exact (d desc, idx asc) merge in LDS (R3-proven).
// Block 256 thr: lane=p (64), wave=scanner (4). Grid 8b x 64 pranges = 512.
// ---------------------------------------------------------------------------
__global__ __launch_bounds__(256) void k_knn1(const float4* __restrict__ qpack,
                                              int* __restrict__ idx1) {
  __shared__ float cd[64][4][3];
  __shared__ int   ci[64][4][3];
  const int b     = blockIdx.x >> 6;
  const int pr    = blockIdx.x & 63;
  const int pbase = pr * 64;
  const int t = threadIdx.x;
  const int p = t & 63;
  const int s = __builtin_amdgcn_readfirstlane(t >> 6);   // wave-uniform 0..3

  // per-lane p coords (one-time vector load)
  const float4 pv = qpack[b * NPTS + pbase + p];
  const float p2x = 2.f * pv.x, p2y = 2.f * pv.y, p2z = 2.f * pv.z;

  // wave-uniform chunk base -> s_load candidates
  const float4* __restrict__ qp = qpack + b * NPTS + s * 1024;

  float d0 = -INFINITY, d1 = -INFINITY, d2 = -INFINITY;
  int   i0 = 0x7fffffff, i1 = 0x7fffffff, i2 = 0x7fffffff;
  const int mstart = s * 1024;

#pragma unroll 8
  for (int j = 0; j < 1024; ++j) {
    float4 q = qp[j];                    // uniform address: s_load_dwordx4
    float d = fmaf(p2x, q.x, fmaf(p2y, q.y, fmaf(p2z, q.z, q.w)));
    if (d > d2) {                        // per-lane insert, wave-rare late
      int m = mstart + j;
      if (d > d1) {
        bool g0 = d > d0;
        d2 = d1;            i2 = i1;
        d1 = g0 ? d0 : d;   i1 = g0 ? i0 : m;
        d0 = g0 ? d : d0;   i0 = g0 ? m : i0;
      } else {
        d2 = d; i2 = m;
      }
    }
  }

  cd[p][s][0] = d0; cd[p][s][1] = d1; cd[p][s][2] = d2;
  ci[p][s][0] = i0; ci[p][s][1] = i1; ci[p][s][2] = i2;
  __syncthreads();

  // exact (d desc, idx asc) merge over the 4 scanners' top-3 lists
  if (t < 64) {
    int* op = idx1 + (b * NPTS + pbase + t) * 3;
    float pd = INFINITY; int pi = -1;
    for (int r = 0; r < 3; ++r) {
      float bd = -INFINITY; int bi = 0x7fffffff;
      for (int sc = 0; sc < 4; ++sc) {
        for (int kk = 0; kk < 3; ++kk) {
          float dv = cd[t][sc][kk]; int iv = ci[t][sc][kk];
          bool allowed = (dv < pd) || (dv == pd && iv > pi);
          bool better  = (dv > bd) || (dv == bd && iv < bi);
          if (allowed && better) { bd = dv; bi = iv; }
        }
      }
      op[r] = bi;
      pd = bd; pi = bi;
    }
  }
}

// ---------------------------------------------------------------------------
// K2: h[b,o,k,n] = sum_c w1[o,c] * F(c,k,n), partial max over n.
// F(c,k,n): ofs = c*12288 + k*4096 + n ; n'=ofs/18, k'=(ofs%18)/6, c'=ofs%6;
//   c'<3 : x[j*3+c'] - x[n'*3+c'] with j = idx1[n'][k'] ; else x[n'*3+c'-3].
// Gathers go straight to L2. Grid 8*3*32 blocks (tile = 128 n); pmax written
// transposed: pmax[((b*3+kk)*64+o)*32 + tile].
// ---------------------------------------------------------------------------
__global__ __launch_bounds__(256) void k_convmax(const float* __restrict__ x,
                                                 const int* __restrict__ idx1,
                                                 const float* __restrict__ w1,
                                                 float* __restrict__ pmax) {
  __shared__ float4 Ft4[128][2];         // row: f0..f3 | f4,f5,--,--
  __shared__ float  w1s[384];
  __shared__ float  smax[4][64];
  const int b    = blockIdx.x / 96;      // 96 = 3*32 blocks per batch
  const int rr   = blockIdx.x - b * 96;
  const int kk   = rr >> 5;
  const int tile = rr & 31;
  const int t = threadIdx.x;
  for (int i = t; i < 384; i += 256) w1s[i] = w1[i];
  const float* xb = x + b * 12288;
  const int*   ib = idx1 + b * 12288;

  const int tn = t & 127, ch = t >> 7;   // 2 threads per n, 3 channels each
  const int n = tile * 128 + tn;
  float* ftrow = (float*)&Ft4[tn][0];
#pragma unroll
  for (int j = 0; j < 3; ++j) {
    int c = ch * 3 + j;
    int ofs = c * 12288 + kk * 4096 + n;
    int np  = ofs / 18;
    int rem = ofs - np * 18;
    int kp  = rem / 6;
    int cp  = rem - kp * 6;
    float val;
    if (cp < 3) {
      int jj = ib[np * 3 + kp];
      val = xb[jj * 3 + cp] - xb[np * 3 + cp];
    } else {
      val = xb[np * 3 + cp - 3];
    }
    ftrow[c] = val;
  }
  __syncthreads();

  const int o = t & 63, sub = t >> 6;
  float w[6];
#pragma unroll
  for (int c = 0; c < 6; ++c) w[c] = w1s[o * 6 + c];
  const int base = sub * 32;
  float mx = -INFINITY;

  float4 ra[4][2];
#pragma unroll
  for (int r = 0; r < 4; ++r) { ra[r][0] = Ft4[base + r][0]; ra[r][1] = Ft4[base + r][1]; }

  for (int i = 0; i < 32; i += 8) {
    float4 rb[4][2];
#pragma unroll
    for (int r = 0; r < 4; ++r) {
      rb[r][0] = Ft4[base + i + 4 + r][0];
      rb[r][1] = Ft4[base + i + 4 + r][1];
    }
#pragma unroll
    for (int r = 0; r < 4; ++r) {
      float h = w[0] * ra[r][0].x;
      h = fmaf(w[1], ra[r][0].y, h);
      h = fmaf(w[2], ra[r][0].z, h);
      h = fmaf(w[3], ra[r][0].w, h);
      h = fmaf(w[4], ra[r][1].x, h);
      h = fmaf(w[5], ra[r][1].y, h);
      mx = fmaxf(mx, h);
    }
#pragma unroll
    for (int r = 0; r < 4; ++r) {
      int nr = base + ((i + 8 + r) & 31);
      ra[r][0] = Ft4[nr][0]; ra[r][1] = Ft4[nr][1];
    }
#pragma unroll
    for (int r = 0; r < 4; ++r) {
      float h = w[0] * rb[r][0].x;
      h = fmaf(w[1], rb[r][0].y, h);
      h = fmaf(w[2], rb[r][0].z, h);
      h = fmaf(w[3], rb[r][0].w, h);
      h = fmaf(w[4], rb[r][1].x, h);
      h = fmaf(w[5], rb[r][1].y, h);
      mx = fmaxf(mx, h);
    }
  }
  smax[sub][o] = mx;
  __syncthreads();
  if (t < 64) {
    float m01 = fmaxf(smax[0][t], smax[1][t]);
    float m23 = fmaxf(smax[2][t], smax[3][t]);
    pmax[((b * 3 + kk) * 64 + t) * 32 + tile] = fmaxf(m01, m23);
  }
}

// Stable top-3 insert for the tiny tail stages.
__device__ __forceinline__ void top3_insert(float d, int m,
                                            float& d0, float& d1, float& d2,
                                            int& i0, int& i1, int& i2) {
  if (d > d2) {
    bool g1 = d > d1;
    bool g0 = d > d0;
    d2 = g1 ? d1 : d;                 i2 = g1 ? i1 : m;
    d1 = g0 ? d0 : (g1 ? d : d1);     i1 = g0 ? i0 : (g1 ? m : i1);
    d0 = g0 ? d : d0;                 i0 = g0 ? m : i0;
  }
}

// ---------------------------------------------------------------------------
// K3: per-batch tail. Reduce partials -> bn1+leaky -> x1 (64,3); graph-feature
// stages 2..4 (N=64 then 6,6; same ofs/18 decode); p[82]; MLP A/B/C; softmax.
// ---------------------------------------------------------------------------
__global__ __launch_bounds__(256) void k_tail(
    const float* __restrict__ pmax,
    const float* __restrict__ bn1g, const float* __restrict__ bn1b,
    const float* __restrict__ bn1m, const float* __restrict__ bn1v,
    const float* __restrict__ wA, const float* __restrict__ bA,
    const float* __restrict__ bnAg, const float* __restrict__ bnAb,
    const float* __restrict__ bnAm, const float* __restrict__ bnAv,
    const float* __restrict__ wB, const float* __restrict__ bB,
    const float* __restrict__ bnBg, const float* __restrict__ bnBb,
    const float* __restrict__ bnBm, const float* __restrict__ bnBv,
    const float* __restrict__ wC, const float* __restrict__ bC,
    float* __restrict__ out) {
  __shared__ float a1[192];
  __shared__ int   idx2[192];
  __shared__ float a2[18], a3[18], a4[18];
  __shared__ int   idxs[18];
  __shared__ float pv[82];
  __shared__ float hA[256];
  __shared__ float hB[128];
  __shared__ float lg[3];
  const int b = blockIdx.x;
  const int t = threadIdx.x;

  // step 1: x1[o][k] = leaky(bn1(max over 32 tiles))  (bn monotone: g>0)
  if (t < 192) {
    int o = t / 3, k = t - o * 3;
    const float4* p4 = (const float4*)(pmax + ((b * 3 + k) * 64 + o) * 32);
    float4 v[8];
#pragma unroll
    for (int j = 0; j < 8; ++j) v[j] = p4[j];
    float mx = -INFINITY;
#pragma unroll
    for (int j = 0; j < 8; ++j) {
      mx = fmaxf(mx, fmaxf(fmaxf(v[j].x, v[j].y), fmaxf(v[j].z, v[j].w)));
    }
    float inv = bn1g[o] / sqrtf(bn1v[o] + EPSV);
    float val = (mx - bn1m[o]) * inv + bn1b[o];
    a1[o * 3 + k] = val >= 0.f ? val : 0.2f * val;
  }
  __syncthreads();

  // step 2: KNN over 64 points, P_n = (a1[n], a1[64+n], a1[128+n])
  if (t < 64) {
    float px = a1[t], py = a1[64 + t], pz = a1[128 + t];
    float pp = px * px; pp = fmaf(py, py, pp); pp = fmaf(pz, pz, pp);
    float d0 = -INFINITY, d1 = -INFINITY, d2 = -INFINITY;
    int i0 = 0, i1 = 0, i2 = 0;
#pragma unroll 8
    for (int m = 0; m < 64; ++m) {
      float qx = a1[m], qy = a1[64 + m], qz = a1[128 + m];
      float qq = qx * qx; qq = fmaf(qy, qy, qq); qq = fmaf(qz, qz, qq);
      float dot = px * qx; dot = fmaf(py, qy, dot); dot = fmaf(pz, qz, dot);
      float d = 2.f * dot - pp - qq;
      top3_insert(d, m, d0, d1, d2, i0, i1, i2);
    }
    idx2[t * 3 + 0] = i0; idx2[t * 3 + 1] = i1; idx2[t * 3 + 2] = i2;
  }
  __syncthreads();

  // step 3: x2[o][kk] = max_nn F2(ofs = o*192 + kk*64 + nn)
  if (t < 18) {
    int o = t / 3, kk = t - o * 3;
    float mx = -INFINITY;
#pragma unroll 8
    for (int nn = 0; nn < 64; ++nn) {
      int ofs = o * 192 + kk * 64 + nn;
      int np = ofs / 18; int rem = ofs - np * 18;
      int kp = rem / 6;  int cp  = rem - kp * 6;
      float val = (cp < 3) ? (a1[idx2[np * 3 + kp] * 3 + cp] - a1[np * 3 + cp])
                           : a1[np * 3 + cp - 3];
      mx = fmaxf(mx, val);
    }
    a2[t] = mx;
  }
  __syncthreads();

  // steps 4-5: N=6 graph-feature twice (a2 -> a3 -> a4)
  for (int stage = 0; stage < 2; ++stage) {
    const float* src = (stage == 0) ? a2 : a3;
    float*       dst = (stage == 0) ? a3 : a4;
    if (t < 6) {
      float px = src[t], py = src[6 + t], pz = src[12 + t];
      float pp = px * px; pp = fmaf(py, py, pp); pp = fmaf(pz, pz, pp);
      float d0 = -INFINITY, d1 = -INFINITY, d2 = -INFINITY;
      int i0 = 0, i1 = 0, i2 = 0;
#pragma unroll
      for (int m = 0; m < 6; ++m) {
        float qx = src[m], qy = src[6 + m], qz = src[12 + m];
        float qq = qx * qx; qq = fmaf(qy, qy, qq); qq = fmaf(qz, qz, qq);
        float dot = px * qx; dot = fmaf(py, qy, dot); dot = fmaf(pz, qz, dot);
        float d = 2.f * dot - pp - qq;
        top3_insert(d, m, d0, d1, d2, i0, i1, i2);
      }
      idxs[t * 3 + 0] = i0; idxs[t * 3 + 1] = i1; idxs[t * 3 + 2] = i2;
    }
    __syncthreads();
    if (t < 18) {
      int o = t / 3, kk = t - o * 3;
      float mx = -INFINITY;
#pragma unroll
      for (int nn = 0; nn < 6; ++nn) {
        int ofs = o * 18 + kk * 6 + nn;
        int np = ofs / 18; int rem = ofs - np * 18;
        int kp = rem / 6;  int cp  = rem - kp * 6;
        float val = (cp < 3) ? (src[idxs[np * 3 + kp] * 3 + cp] - src[np * 3 + cp])
                             : src[np * 3 + cp - 3];
        mx = fmaxf(mx, val);
      }
      dst[t] = mx;
    }
    __syncthreads();
  }

  // step 6: p[82] = max over k
  if (t < 82) {
    float mx;
    if (t < 64)      { int o = t;      mx = fmaxf(fmaxf(a1[o*3], a1[o*3+1]), a1[o*3+2]); }
    else if (t < 70) { int o = t - 64; mx = fmaxf(fmaxf(a2[o*3], a2[o*3+1]), a2[o*3+2]); }
    else if (t < 76) { int o = t - 70; mx = fmaxf(fmaxf(a3[o*3], a3[o*3+1]), a3[o*3+2]); }
    else             { int o = t - 76; mx = fmaxf(fmaxf(a4[o*3], a4[o*3+1]), a4[o*3+2]); }
    pv[t] = mx;
  }
  __syncthreads();

  // step 7: hA = leaky(bnA(p @ wA.T + bA))  (256 outputs)
  {
    float acc = bA[t];
    const float* wr = wA + t * 82;
#pragma unroll 8
    for (int i = 0; i < 82; ++i) acc = fmaf(wr[i], pv[i], acc);
    float inv = bnAg[t] / sqrtf(bnAv[t] + EPSV);
    float v = (acc - bnAm[t]) * inv + bnAb[t];
    hA[t] = v >= 0.f ? v : 0.2f * v;
  }
  __syncthreads();

  // step 8: hB (128 outputs)
  if (t < 128) {
    float acc = bB[t];
    const float4* wr4 = (const float4*)(wB + t * 256);
#pragma unroll 8
    for (int i = 0; i < 64; ++i) {
      float4 wv = wr4[i];
      acc = fmaf(wv.x, hA[4 * i + 0], acc);
      acc = fmaf(wv.y, hA[4 * i + 1], acc);
      acc = fmaf(wv.z, hA[4 * i + 2], acc);
      acc = fmaf(wv.w, hA[4 * i + 3], acc);
    }
    float inv = bnBg[t] / sqrtf(bnBv[t] + EPSV);
    float v = (acc - bnBm[t]) * inv + bnBb[t];
    hB[t] = v >= 0.f ? v : 0.2f * v;
  }
  __syncthreads();

  // step 9: logits + softmax
  if (t < 3) {
    float acc = bC[t];
    const float* wr = wC + t * 128;
#pragma unroll 8
    for (int i = 0; i < 128; ++i) acc = fmaf(wr[i], hB[i], acc);
    lg[t] = acc;
  }
  __syncthreads();
  if (t == 0) {
    float m = fmaxf(fmaxf(lg[0], lg[1]), lg[2]);
    float e0 = expf(lg[0] - m), e1 = expf(lg[1] - m), e2 = expf(lg[2] - m);
    float s = e0 + e1 + e2;
    out[b * 3 + 0] = e0 / s;
    out[b * 3 + 1] = e1 / s;
    out[b * 3 + 2] = e2 / s;
  }
}

extern "C" void kernel_launch(void* const* d_in, const int* in_sizes, int n_in,
                              void* d_out, int out_size, void* d_ws, size_t ws_size,
                              hipStream_t stream) {
  (void)in_sizes; (void)n_in; (void)out_size; (void)ws_size;
  const float* x    = (const float*)d_in[0];
  const float* w1   = (const float*)d_in[1];
  const float* wA   = (const float*)d_in[2];
  const float* bA   = (const float*)d_in[3];
  const float* wB   = (const float*)d_in[4];
  const float* bB   = (const float*)d_in[5];
  const float* wC   = (const float*)d_in[6];
  const float* bC   = (const float*)d_in[7];
  const float* bn1g = (const float*)d_in[8];
  const float* bn1b = (const float*)d_in[9];
  const float* bn1m = (const float*)d_in[10];
  const float* bn1v = (const float*)d_in[11];
  const float* bnAg = (const float*)d_in[12];
  const float* bnAb = (const float*)d_in[13];
  const float* bnAm = (const float*)d_in[14];
  const float* bnAv = (const float*)d_in[15];
  const float* bnBg = (const float*)d_in[16];
  const float* bnBb = (const float*)d_in[17];
  const float* bnBm = (const float*)d_in[18];
  const float* bnBv = (const float*)d_in[19];
  float* out = (float*)d_out;

  // ws layout: idx1 @0 (384 KB); qpack @384 KB (512 KB, live only during
  // k_knn1); pmax overlays qpack @384 KB (192 KB, written by k_convmax AFTER
  // k_knn1 completes -- stream-ordered, so the overlay is safe).
  int*    idx1  = (int*)d_ws;
  float4* qpack = (float4*)((char*)d_ws + 8 * 4096 * 3 * 4);
  float*  pmax  = (float*)((char*)d_ws + 8 * 4096 * 3 * 4);

  k_pack<<<128, 256, 0, stream>>>(x, qpack);
  k_knn1<<<512, 256, 0, stream>>>(qpack, idx1);
  k_convmax<<<768, 256, 0, stream>>>(x, idx1, w1, pmax);
  k_tail<<<8, 256, 0, stream>>>(pmax,
                                bn1g, bn1b, bn1m, bn1v,
                                wA, bA, bnAg, bnAb, bnAm, bnAv,
                                wB, bB, bnBg, bnBb, bnBm, bnBv,
                                wC, bC, out);
}

// Round 13
// 176.250 us; speedup vs baseline: 1.3720x; 1.3720x over previous
//
#include <hip/hip_runtime.h>
#include <math.h>

#define NPTS 4096
#define EPSV 1e-5f

// 16-lane xor-butterfly max via DPP (VALU-rate, no LDS pipe).
template <int CTRL>
__device__ __forceinline__ float dpp_max(float v) {
#if __has_builtin(__builtin_amdgcn_update_dpp)
  int o = __builtin_amdgcn_update_dpp(0, __float_as_int(v), CTRL, 0xF, 0xF, true);
  return fmaxf(v, __int_as_float(o));
#else
  int lanemask = (CTRL == 0xB1) ? 1 : (CTRL == 0x4E) ? 2 : (CTRL == 0x141) ? 7 : 15;
  return fmaxf(v, __shfl_xor(v, lanemask, 16));
#endif
}

// ---------------------------------------------------------------------------
// K1: stage-1 KNN, m-in-registers two-phase. BEST MEASURED VARIANT (R8,
// 177.34 us total / knn1 53.2 us) -- reverted to after R9-R12 regressions.
//
// PLATEAU NOTE (R3-R12 evidence): knn1 has a ~53 us floor reached by two
// independent mechanisms: (a) R3-style LDS broadcast is VALU-issue bound
// (73% busy, ~22 instr/iter incl. top-3 insert at ~70% wave-taken rate);
// (b) this two-phase variant is L2-BW bound -- the allocator rematerializes
// the 32 per-thread q floats as per-iteration global loads (~6.3 MB/CU
// against a ~7 MB/53us per-CU L2 share). Six attempts to force register
// residency (named scalars R7, no-LDS-copy R8, waves_per_eu R9, asm-PIN R10,
// 4-pt shrink R11, scalar-pipe R12) all failed: the ROCm allocator reroutes
// bulk per-thread state through LDS/L2/AGPR at a 2-3x tax. Remaining paper
// designs (branchless med3 + exact-theta rescan, multi-p broadcast) model at
// 40-45 us -- <8 us net on a 177 us total with a 7/7 redesign failure record.
// The gap (total - knn1) is fixed at 124-129 us across all ten rounds
// (harness restore/poison + convmax + tail).
//
// Points are flat-view columns P_n = (buf[n], buf[4096+n], buf[8192+n]).
// key(q) = 2p.q - |q|^2 (per-p constant shift dropped; order-preserving).
// Thread t owns m in [8t,8t+8); 16-lane group g covers 128 m. Phase A:
// per-(p,group) max via 24 fma + 7 max + 4 dpp-max + 1 unconditional
// ds_write. theta[p] = 3rd-largest of 32 group maxes (provable lower bound
// on the true 3rd key: 3 distinct positions own the top-3 group maxes).
// Rescan: one ds_read_b64 (theta|hitmask) per p; hit groups recompute keys,
// append (key,m) via LDS atomics. Final: exact (key desc, idx asc) top-3
// among stored candidates = lax.top_k stable order.
// ---------------------------------------------------------------------------
__global__ __launch_bounds__(512, 4) void k_knn1(const float* __restrict__ x,
                                                 int* __restrict__ idx1) {
  __shared__ float4 ppre[64];            // (2px,2py,2pz,0)
  __shared__ float  scmax[64][32];       // 8 KB
  __shared__ float2 thmask[65];          // theta | hitmask (+pad)
  __shared__ int    cnt[64];
  __shared__ float  candk[64][24];       // 6 KB
  __shared__ int    candi[64][24];       // 6 KB
  __shared__ float  dummy[512];
  const int b     = blockIdx.x >> 6;     // 64 p-ranges per batch
  const int pr    = blockIdx.x & 63;
  const int pbase = pr * 64;
  const float* xb = x + b * (NPTS * 3);
  const int t = threadIdx.x;
  const int g = t >> 4;                  // group 0..31 (128 m each)

  // ---- stage: coalesced global loads -> named regs ----
  float q0x, q1x, q2x, q3x, q4x, q5x, q6x, q7x;
  float q0y, q1y, q2y, q3y, q4y, q5y, q6y, q7y;
  float q0z, q1z, q2z, q3z, q4z, q5z, q6z, q7z;
  {
    const float4* X = (const float4*)(xb + 8 * t);
    const float4* Y = (const float4*)(xb + NPTS + 8 * t);
    const float4* Z = (const float4*)(xb + 2 * NPTS + 8 * t);
    float4 x0 = X[0], x1 = X[1];
    float4 y0 = Y[0], y1 = Y[1];
    float4 z0 = Z[0], z1 = Z[1];
    q0x = x0.x; q1x = x0.y; q2x = x0.z; q3x = x0.w;
    q4x = x1.x; q5x = x1.y; q6x = x1.z; q7x = x1.w;
    q0y = y0.x; q1y = y0.y; q2y = y0.z; q3y = y0.w;
    q4y = y1.x; q5y = y1.y; q6y = y1.z; q7y = y1.w;
    q0z = z0.x; q1z = z0.y; q2z = z0.z; q3z = z0.w;
    q4z = z1.x; q5z = z1.y; q6z = z1.z; q7z = z1.w;
  }
  const float q0w = -fmaf(q0z, q0z, fmaf(q0y, q0y, q0x * q0x));
  const float q1w = -fmaf(q1z, q1z, fmaf(q1y, q1y, q1x * q1x));
  const float q2w = -fmaf(q2z, q2z, fmaf(q2y, q2y, q2x * q2x));
  const float q3w = -fmaf(q3z, q3z, fmaf(q3y, q3y, q3x * q3x));
  const float q4w = -fmaf(q4z, q4z, fmaf(q4y, q4y, q4x * q4x));
  const float q5w = -fmaf(q5z, q5z, fmaf(q5y, q5y, q5x * q5x));
  const float q6w = -fmaf(q6z, q6z, fmaf(q6y, q6y, q6x * q6x));
  const float q7w = -fmaf(q7z, q7z, fmaf(q7y, q7y, q7x * q7x));
  if (t < 64) {
    float px = xb[pbase + t];
    float py = xb[NPTS + pbase + t];
    float pz = xb[2 * NPTS + pbase + t];
    ppre[t] = make_float4(2.f * px, 2.f * py, 2.f * pz, 0.f);
    cnt[t] = 0;
  }
  __syncthreads();

  // ---- phase A: per-(p,group) max, unconditional write ----
  {
    float* wptr = ((t & 15) == 0) ? &scmax[0][g] : &dummy[t];
    const int wstep = ((t & 15) == 0) ? 32 : 0;
#pragma unroll 4
    for (int p = 0; p < 64; ++p) {
      float4 P = ppre[p];
      float k0 = fmaf(P.x, q0x, fmaf(P.y, q0y, fmaf(P.z, q0z, q0w)));
      float k1 = fmaf(P.x, q1x, fmaf(P.y, q1y, fmaf(P.z, q1z, q1w)));
      float k2 = fmaf(P.x, q2x, fmaf(P.y, q2y, fmaf(P.z, q2z, q2w)));
      float k3 = fmaf(P.x, q3x, fmaf(P.y, q3y, fmaf(P.z, q3z, q3w)));
      float k4 = fmaf(P.x, q4x, fmaf(P.y, q4y, fmaf(P.z, q4z, q4w)));
      float k5 = fmaf(P.x, q5x, fmaf(P.y, q5y, fmaf(P.z, q5z, q5w)));
      float k6 = fmaf(P.x, q6x, fmaf(P.y, q6y, fmaf(P.z, q6z, q6w)));
      float k7 = fmaf(P.x, q7x, fmaf(P.y, q7y, fmaf(P.z, q7z, q7w)));
      float v = fmaxf(fmaxf(fmaxf(k0, k1), fmaxf(k2, k3)),
                      fmaxf(fmaxf(k4, k5), fmaxf(k6, k7)));
      v = dpp_max<0xB1>(v);              // xor1
      v = dpp_max<0x4E>(v);              // xor2
      v = dpp_max<0x141>(v);             // xor7  (row_half_mirror)
      v = dpp_max<0x140>(v);             // xor15 (row_mirror)
      *wptr = v;
      wptr += wstep;
    }
  }
  __syncthreads();

  // ---- theta[p] (3rd largest of 32 group maxes) + 32-bit hit mask ----
  if (t < 64) {
    const float4* row = (const float4*)scmax[t];
    float4 r[8];
#pragma unroll
    for (int i = 0; i < 8; ++i) r[i] = row[i];
    float d0 = -INFINITY, d1 = -INFINITY, d2 = -INFINITY;
#pragma unroll
    for (int i = 0; i < 8; ++i) {
      float va[4] = {r[i].x, r[i].y, r[i].z, r[i].w};
#pragma unroll
      for (int u = 0; u < 4; ++u) {
        float v = va[u];
        float nd2 = fmaxf(d2, fminf(d1, v));
        float nd1 = fmaxf(d1, fminf(d0, v));
        d0 = fmaxf(d0, v); d1 = nd1; d2 = nd2;
      }
    }
    unsigned mask = 0;
#pragma unroll
    for (int i = 0; i < 8; ++i) {
      float va[4] = {r[i].x, r[i].y, r[i].z, r[i].w};
#pragma unroll
      for (int u = 0; u < 4; ++u)
        mask |= (va[u] >= d2) ? (1u << (4 * i + u)) : 0u;
    }
    thmask[t] = make_float2(d2, __uint_as_float(mask));
  } else if (t == 64) {
    thmask[64] = make_float2(0.f, 0.f);
  }
  __syncthreads();

  // ---- rescan: one b64 read per p; hit groups recompute keys from regs ----
  {
    float2 tm = thmask[0];
    for (int p = 0; p < 64; ++p) {
      float2 ntm = thmask[p + 1];
      unsigned mask = __float_as_uint(tm.y);
      if ((mask >> g) & 1u) {
        float th = tm.x;
        float4 P = ppre[p];
        float kk[8];
        kk[0] = fmaf(P.x, q0x, fmaf(P.y, q0y, fmaf(P.z, q0z, q0w)));
        kk[1] = fmaf(P.x, q1x, fmaf(P.y, q1y, fmaf(P.z, q1z, q1w)));
        kk[2] = fmaf(P.x, q2x, fmaf(P.y, q2y, fmaf(P.z, q2z, q2w)));
        kk[3] = fmaf(P.x, q3x, fmaf(P.y, q3y, fmaf(P.z, q3z, q3w)));
        kk[4] = fmaf(P.x, q4x, fmaf(P.y, q4y, fmaf(P.z, q4z, q4w)));
        kk[5] = fmaf(P.x, q5x, fmaf(P.y, q5y, fmaf(P.z, q5z, q5w)));
        kk[6] = fmaf(P.x, q6x, fmaf(P.y, q6y, fmaf(P.z, q6z, q6w)));
        kk[7] = fmaf(P.x, q7x, fmaf(P.y, q7y, fmaf(P.z, q7z, q7w)));
#pragma unroll
        for (int j = 0; j < 8; ++j) {
          if (kk[j] >= th) {
            int c = atomicAdd(&cnt[p], 1);
            if (c < 24) { candk[p][c] = kk[j]; candi[p][c] = 8 * t + j; }
          }
        }
      }
      tm = ntm;
    }
  }
  __syncthreads();

  // ---- final: exact (key desc, idx asc) top-3 among stored candidates ----
  if (t < 64) {
    int c = cnt[t]; if (c > 24) c = 24;
    int* op = idx1 + (b * NPTS + pbase + t) * 3;
    float pd = INFINITY; int pi = -1;
    for (int r = 0; r < 3; ++r) {
      float bd = -INFINITY; int bi = 0x7fffffff;
      for (int cc = 0; cc < c; ++cc) {
        float kv = candk[t][cc];
        int m = candi[t][cc];
        bool allowed = (kv < pd) || (kv == pd && m > pi);
        bool better  = (kv > bd) || (kv == bd && m < bi);
        if (allowed && better) { bd = kv; bi = m; }
      }
      op[r] = bi;
      pd = bd; pi = bi;
    }
  }
}

// ---------------------------------------------------------------------------
// K2: h[b,o,k,n] = sum_c w1[o,c] * F(c,k,n), partial max over n.
// F(c,k,n): ofs = c*12288 + k*4096 + n ; n'=ofs/18, k'=(ofs%18)/6, c'=ofs%6;
//   c'<3 : x[j*3+c'] - x[n'*3+c'] with j = idx1[n'][k'] ; else x[n'*3+c'-3].
// Gathers go straight to L2 (R3 showed LDS staging of x costs +3.6us).
// Grid 8*3*32 blocks (tile = 128 n); pmax written transposed:
// pmax[((b*3+kk)*64+o)*32 + tile].
// ---------------------------------------------------------------------------
__global__ __launch_bounds__(256) void k_convmax(const float* __restrict__ x,
                                                 const int* __restrict__ idx1,
                                                 const float* __restrict__ w1,
                                                 float* __restrict__ pmax) {
  __shared__ float4 Ft4[128][2];         // row: f0..f3 | f4,f5,--,--
  __shared__ float  w1s[384];
  __shared__ float  smax[4][64];
  const int b    = blockIdx.x / 96;      // 96 = 3*32 blocks per batch
  const int rr   = blockIdx.x - b * 96;
  const int kk   = rr >> 5;
  const int tile = rr & 31;
  const int t = threadIdx.x;
  for (int i = t; i < 384; i += 256) w1s[i] = w1[i];
  const float* xb = x + b * 12288;
  const int*   ib = idx1 + b * 12288;

  const int tn = t & 127, ch = t >> 7;   // 2 threads per n, 3 channels each
  const int n = tile * 128 + tn;
  float* ftrow = (float*)&Ft4[tn][0];
#pragma unroll
  for (int j = 0; j < 3; ++j) {
    int c = ch * 3 + j;
    int ofs = c * 12288 + kk * 4096 + n;
    int np  = ofs / 18;
    int rem = ofs - np * 18;
    int kp  = rem / 6;
    int cp  = rem - kp * 6;
    float val;
    if (cp < 3) {
      int jj = ib[np * 3 + kp];
      val = xb[jj * 3 + cp] - xb[np * 3 + cp];
    } else {
      val = xb[np * 3 + cp - 3];
    }
    ftrow[c] = val;
  }
  __syncthreads();

  const int o = t & 63, sub = t >> 6;
  float w[6];
#pragma unroll
  for (int c = 0; c < 6; ++c) w[c] = w1s[o * 6 + c];
  const int base = sub * 32;
  float mx = -INFINITY;

  float4 ra[4][2];
#pragma unroll
  for (int r = 0; r < 4; ++r) { ra[r][0] = Ft4[base + r][0]; ra[r][1] = Ft4[base + r][1]; }

  for (int i = 0; i < 32; i += 8) {
    float4 rb[4][2];
#pragma unroll
    for (int r = 0; r < 4; ++r) {
      rb[r][0] = Ft4[base + i + 4 + r][0];
      rb[r][1] = Ft4[base + i + 4 + r][1];
    }
#pragma unroll
    for (int r = 0; r < 4; ++r) {
      float h = w[0] * ra[r][0].x;
      h = fmaf(w[1], ra[r][0].y, h);
      h = fmaf(w[2], ra[r][0].z, h);
      h = fmaf(w[3], ra[r][0].w, h);
      h = fmaf(w[4], ra[r][1].x, h);
      h = fmaf(w[5], ra[r][1].y, h);
      mx = fmaxf(mx, h);
    }
#pragma unroll
    for (int r = 0; r < 4; ++r) {
      int nr = base + ((i + 8 + r) & 31);
      ra[r][0] = Ft4[nr][0]; ra[r][1] = Ft4[nr][1];
    }
#pragma unroll
    for (int r = 0; r < 4; ++r) {
      float h = w[0] * rb[r][0].x;
      h = fmaf(w[1], rb[r][0].y, h);
      h = fmaf(w[2], rb[r][0].z, h);
      h = fmaf(w[3], rb[r][0].w, h);
      h = fmaf(w[4], rb[r][1].x, h);
      h = fmaf(w[5], rb[r][1].y, h);
      mx = fmaxf(mx, h);
    }
  }
  smax[sub][o] = mx;
  __syncthreads();
  if (t < 64) {
    float m01 = fmaxf(smax[0][t], smax[1][t]);
    float m23 = fmaxf(smax[2][t], smax[3][t]);
    pmax[((b * 3 + kk) * 64 + t) * 32 + tile] = fmaxf(m01, m23);
  }
}

// Stable top-3 insert for the tiny tail stages.
__device__ __forceinline__ void top3_insert(float d, int m,
                                            float& d0, float& d1, float& d2,
                                            int& i0, int& i1, int& i2) {
  if (d > d2) {
    bool g1 = d > d1;
    bool g0 = d > d0;
    d2 = g1 ? d1 : d;                 i2 = g1 ? i1 : m;
    d1 = g0 ? d0 : (g1 ? d : d1);     i1 = g0 ? i0 : (g1 ? m : i1);
    d0 = g0 ? d : d0;                 i0 = g0 ? m : i0;
  }
}

// ---------------------------------------------------------------------------
// K3: per-batch tail. Reduce partials -> bn1+leaky -> x1 (64,3); graph-feature
// stages 2..4 (N=64 then 6,6; same ofs/18 decode); p[82]; MLP A/B/C; softmax.
// ---------------------------------------------------------------------------
__global__ __launch_bounds__(256) void k_tail(
    const float* __restrict__ pmax,
    const float* __restrict__ bn1g, const float* __restrict__ bn1b,
    const float* __restrict__ bn1m, const float* __restrict__ bn1v,
    const float* __restrict__ wA, const float* __restrict__ bA,
    const float* __restrict__ bnAg, const float* __restrict__ bnAb,
    const float* __restrict__ bnAm, const float* __restrict__ bnAv,
    const float* __restrict__ wB, const float* __restrict__ bB,
    const float* __restrict__ bnBg, const float* __restrict__ bnBb,
    const float* __restrict__ bnBm, const float* __restrict__ bnBv,
    const float* __restrict__ wC, const float* __restrict__ bC,
    float* __restrict__ out) {
  __shared__ float a1[192];
  __shared__ int   idx2[192];
  __shared__ float a2[18], a3[18], a4[18];
  __shared__ int   idxs[18];
  __shared__ float pv[82];
  __shared__ float hA[256];
  __shared__ float hB[128];
  __shared__ float lg[3];
  const int b = blockIdx.x;
  const int t = threadIdx.x;

  // step 1: x1[o][k] = leaky(bn1(max over 32 tiles))  (bn monotone: g>0)
  if (t < 192) {
    int o = t / 3, k = t - o * 3;
    const float4* p4 = (const float4*)(pmax + ((b * 3 + k) * 64 + o) * 32);
    float4 v[8];
#pragma unroll
    for (int j = 0; j < 8; ++j) v[j] = p4[j];
    float mx = -INFINITY;
#pragma unroll
    for (int j = 0; j < 8; ++j) {
      mx = fmaxf(mx, fmaxf(fmaxf(v[j].x, v[j].y), fmaxf(v[j].z, v[j].w)));
    }
    float inv = bn1g[o] / sqrtf(bn1v[o] + EPSV);
    float val = (mx - bn1m[o]) * inv + bn1b[o];
    a1[o * 3 + k] = val >= 0.f ? val : 0.2f * val;
  }
  __syncthreads();

  // step 2: KNN over 64 points, P_n = (a1[n], a1[64+n], a1[128+n])
  if (t < 64) {
    float px = a1[t], py = a1[64 + t], pz = a1[128 + t];
    float pp = px * px; pp = fmaf(py, py, pp); pp = fmaf(pz, pz, pp);
    float d0 = -INFINITY, d1 = -INFINITY, d2 = -INFINITY;
    int i0 = 0, i1 = 0, i2 = 0;
#pragma unroll 8
    for (int m = 0; m < 64; ++m) {
      float qx = a1[m], qy = a1[64 + m], qz = a1[128 + m];
      float qq = qx * qx; qq = fmaf(qy, qy, qq); qq = fmaf(qz, qz, qq);
      float dot = px * qx; dot = fmaf(py, qy, dot); dot = fmaf(pz, qz, dot);
      float d = 2.f * dot - pp - qq;
      top3_insert(d, m, d0, d1, d2, i0, i1, i2);
    }
    idx2[t * 3 + 0] = i0; idx2[t * 3 + 1] = i1; idx2[t * 3 + 2] = i2;
  }
  __syncthreads();

  // step 3: x2[o][kk] = max_nn F2(ofs = o*192 + kk*64 + nn)
  if (t < 18) {
    int o = t / 3, kk = t - o * 3;
    float mx = -INFINITY;
#pragma unroll 8
    for (int nn = 0; nn < 64; ++nn) {
      int ofs = o * 192 + kk * 64 + nn;
      int np = ofs / 18; int rem = ofs - np * 18;
      int kp = rem / 6;  int cp  = rem - kp * 6;
      float val = (cp < 3) ? (a1[idx2[np * 3 + kp] * 3 + cp] - a1[np * 3 + cp])
                           : a1[np * 3 + cp - 3];
      mx = fmaxf(mx, val);
    }
    a2[t] = mx;
  }
  __syncthreads();

  // steps 4-5: N=6 graph-feature twice (a2 -> a3 -> a4)
  for (int stage = 0; stage < 2; ++stage) {
    const float* src = (stage == 0) ? a2 : a3;
    float*       dst = (stage == 0) ? a3 : a4;
    if (t < 6) {
      float px = src[t], py = src[6 + t], pz = src[12 + t];
      float pp = px * px; pp = fmaf(py, py, pp); pp = fmaf(pz, pz, pp);
      float d0 = -INFINITY, d1 = -INFINITY, d2 = -INFINITY;
      int i0 = 0, i1 = 0, i2 = 0;
#pragma unroll
      for (int m = 0; m < 6; ++m) {
        float qx = src[m], qy = src[6 + m], qz = src[12 + m];
        float qq = qx * qx; qq = fmaf(qy, qy, qq); qq = fmaf(qz, qz, qq);
        float dot = px * qx; dot = fmaf(py, qy, dot); dot = fmaf(pz, qz, dot);
        float d = 2.f * dot - pp - qq;
        top3_insert(d, m, d0, d1, d2, i0, i1, i2);
      }
      idxs[t * 3 + 0] = i0; idxs[t * 3 + 1] = i1; idxs[t * 3 + 2] = i2;
    }
    __syncthreads();
    if (t < 18) {
      int o = t / 3, kk = t - o * 3;
      float mx = -INFINITY;
#pragma unroll
      for (int nn = 0; nn < 6; ++nn) {
        int ofs = o * 18 + kk * 6 + nn;
        int np = ofs / 18; int rem = ofs - np * 18;
        int kp = rem / 6;  int cp  = rem - kp * 6;
        float val = (cp < 3) ? (src[idxs[np * 3 + kp] * 3 + cp] - src[np * 3 + cp])
                             : src[np * 3 + cp - 3];
        mx = fmaxf(mx, val);
      }
      dst[t] = mx;
    }
    __syncthreads();
  }

  // step 6: p[82] = max over k
  if (t < 82) {
    float mx;
    if (t < 64)      { int o = t;      mx = fmaxf(fmaxf(a1[o*3], a1[o*3+1]), a1[o*3+2]); }
    else if (t < 70) { int o = t - 64; mx = fmaxf(fmaxf(a2[o*3], a2[o*3+1]), a2[o*3+2]); }
    else if (t < 76) { int o = t - 70; mx = fmaxf(fmaxf(a3[o*3], a3[o*3+1]), a3[o*3+2]); }
    else             { int o = t - 76; mx = fmaxf(fmaxf(a4[o*3], a4[o*3+1]), a4[o*3+2]); }
    pv[t] = mx;
  }
  __syncthreads();

  // step 7: hA = leaky(bnA(p @ wA.T + bA))  (256 outputs)
  {
    float acc = bA[t];
    const float* wr = wA + t * 82;
#pragma unroll 8
    for (int i = 0; i < 82; ++i) acc = fmaf(wr[i], pv[i], acc);
    float inv = bnAg[t] / sqrtf(bnAv[t] + EPSV);
    float v = (acc - bnAm[t]) * inv + bnAb[t];
    hA[t] = v >= 0.f ? v : 0.2f * v;
  }
  __syncthreads();

  // step 8: hB (128 outputs)
  if (t < 128) {
    float acc = bB[t];
    const float4* wr4 = (const float4*)(wB + t * 256);
#pragma unroll 8
    for (int i = 0; i < 64; ++i) {
      float4 wv = wr4[i];
      acc = fmaf(wv.x, hA[4 * i + 0], acc);
      acc = fmaf(wv.y, hA[4 * i + 1], acc);
      acc = fmaf(wv.z, hA[4 * i + 2], acc);
      acc = fmaf(wv.w, hA[4 * i + 3], acc);
    }
    float inv = bnBg[t] / sqrtf(bnBv[t] + EPSV);
    float v = (acc - bnBm[t]) * inv + bnBb[t];
    hB[t] = v >= 0.f ? v : 0.2f * v;
  }
  __syncthreads();

  // step 9: logits + softmax
  if (t < 3) {
    float acc = bC[t];
    const float* wr = wC + t * 128;
#pragma unroll 8
    for (int i = 0; i < 128; ++i) acc = fmaf(wr[i], hB[i], acc);
    lg[t] = acc;
  }
  __syncthreads();
  if (t == 0) {
    float m = fmaxf(fmaxf(lg[0], lg[1]), lg[2]);
    float e0 = expf(lg[0] - m), e1 = expf(lg[1] - m), e2 = expf(lg[2] - m);
    float s = e0 + e1 + e2;
    out[b * 3 + 0] = e0 / s;
    out[b * 3 + 1] = e1 / s;
    out[b * 3 + 2] = e2 / s;
  }
}

extern "C" void kernel_launch(void* const* d_in, const int* in_sizes, int n_in,
                              void* d_out, int out_size, void* d_ws, size_t ws_size,
                              hipStream_t stream) {
  (void)in_sizes; (void)n_in; (void)out_size; (void)ws_size;
  const float* x    = (const float*)d_in[0];
  const float* w1   = (const float*)d_in[1];
  const float* wA   = (const float*)d_in[2];
  const float* bA   = (const float*)d_in[3];
  const float* wB   = (const float*)d_in[4];
  const float* bB   = (const float*)d_in[5];
  const float* wC   = (const float*)d_in[6];
  const float* bC   = (const float*)d_in[7];
  const float* bn1g = (const float*)d_in[8];
  const float* bn1b = (const float*)d_in[9];
  const float* bn1m = (const float*)d_in[10];
  const float* bn1v = (const float*)d_in[11];
  const float* bnAg = (const float*)d_in[12];
  const float* bnAb = (const float*)d_in[13];
  const float* bnAm = (const float*)d_in[14];
  const float* bnAv = (const float*)d_in[15];
  const float* bnBg = (const float*)d_in[16];
  const float* bnBb = (const float*)d_in[17];
  const float* bnBm = (const float*)d_in[18];
  const float* bnBv = (const float*)d_in[19];
  float* out = (float*)d_out;

  int*   idx1 = (int*)d_ws;                                  // 8*4096*3 ints = 384 KB
  float* pmax = (float*)((char*)d_ws + 8 * 4096 * 3 * 4);    // 8*3*64*32 floats = 192 KB

  k_knn1<<<512, 512, 0, stream>>>(x, idx1);
  k_convmax<<<768, 256, 0, stream>>>(x, idx1, w1, pmax);
  k_tail<<<8, 256, 0, stream>>>(pmax,
                                bn1g, bn1b, bn1m, bn1v,
                                wA, bA, bnAg, bnAb, bnAm, bnAv,
                                wB, bB, bnBg, bnBb, bnBm, bnBv,
                                wC, bC, out);
}